// Round 1
// baseline (98.731 us; speedup 1.0000x reference)
//
#include <hip/hip_runtime.h>
#include <hip/hip_bf16.h>
#include <math.h>

// SupConLoss, B=4096 V=2 D=128, N=8192.
// loss = (1/N) * sum_i [ log(sum_{j!=i} exp(n_i.n_j/T)) - s_pos_i ]
// Fused bf16-MFMA GEMM + exp + row-sum; s_pos via exact fp32 pair dots.

constexpr int   Bsz   = 4096;
constexpr int   Nrows = 8192;
constexpr int   Dd    = 128;
constexpr float TEMPf = 0.07f;
constexpr float EPSN  = 1e-8f;
// exp(x/T) = 2^(x * log2(e)/T)
constexpr float SCALE = 1.4426950408889634f / 0.07f;

constexpr int CHUNKS     = 16;                    // column chunks (grid.x)
constexpr int CHUNK_COLS = Nrows / CHUNKS;        // 512
constexpr int TILE_COLS  = 32;
constexpr int TILES      = CHUNK_COLS / TILE_COLS; // 16

typedef __attribute__((ext_vector_type(8)))  short bf16x8;   // 8 bf16 = 4 VGPRs
typedef __attribute__((ext_vector_type(16))) float floatx16; // MFMA 32x32 C/D

// ws layout: [0,2MB) n bf16[8192][128]; [2MB,+32KB) sumexp f32[8192]; then spos f32[4096]

// ---------------- normalize: features -> bf16 row-normalized n -----------------
__global__ void normalize_k(const float* __restrict__ f, __hip_bfloat16* __restrict__ n) {
    int row  = blockIdx.x * 4 + (threadIdx.x >> 6);   // one wave per row
    int lane = threadIdx.x & 63;
    int v = row >> 12, b = row & (Bsz - 1);           // cf[i] = features[b, v]  (view-major)
    const float* src = f + (size_t)(b * 2 + v) * Dd;
    float2 x = *(const float2*)(src + lane * 2);
    float ss = x.x * x.x + x.y * x.y;
    #pragma unroll
    for (int off = 32; off; off >>= 1) ss += __shfl_xor(ss, off);
    float inv = 1.0f / fmaxf(sqrtf(ss), EPSN);
    __hip_bfloat162 h;
    h.x = __float2bfloat16(x.x * inv);
    h.y = __float2bfloat16(x.y * inv);
    *(__hip_bfloat162*)(n + (size_t)row * Dd + lane * 2) = h;
}

// ---------------- s_pos: exact fp32 dot of the two views of each sample --------
__global__ void pos_k(const float* __restrict__ f, float* __restrict__ spos) {
    int b    = blockIdx.x * 4 + (threadIdx.x >> 6);   // one wave per pair
    int lane = threadIdx.x & 63;
    const float* s0 = f + (size_t)(b * 2) * Dd;       // view 0
    const float* s1 = s0 + Dd;                        // view 1
    float2 a = *(const float2*)(s0 + lane * 2);
    float2 c = *(const float2*)(s1 + lane * 2);
    float ss0 = a.x * a.x + a.y * a.y;
    float ss1 = c.x * c.x + c.y * c.y;
    float dt  = a.x * c.x + a.y * c.y;
    #pragma unroll
    for (int off = 32; off; off >>= 1) {
        ss0 += __shfl_xor(ss0, off);
        ss1 += __shfl_xor(ss1, off);
        dt  += __shfl_xor(dt,  off);
    }
    if (lane == 0) {
        float inv0 = 1.0f / fmaxf(sqrtf(ss0), EPSN);
        float inv1 = 1.0f / fmaxf(sqrtf(ss1), EPSN);
        spos[b] = dt * inv0 * inv1 / TEMPf;
    }
}

// ---------------- main: fused n·n^T -> exp -> row sums -------------------------
// Block: 256 thr (4 waves). Wave tile: 64 rows x 32 cols, K=128.
// A (64 rows x 128) in registers; B tile (32 cols x 128) staged in LDS as
// [k-unit u][col c] with XOR swizzle so ds_read_b128 is conflict-free.
__global__ __launch_bounds__(256, 2)
void main_k(const __hip_bfloat16* __restrict__ nmat, float* __restrict__ sumexp) {
    __shared__ char lds[TILE_COLS * 256];   // 8 KB: 16 units x 32 cols x 16 B
    const int tid  = threadIdx.x;
    const int wid  = tid >> 6;
    const int lane = tid & 63;
    const int lo   = lane & 31;
    const int hi   = lane >> 5;
    const int rbase = blockIdx.y * 256 + wid * 64;   // wave's 64 rows
    const int cbase = blockIdx.x * CHUNK_COLS;
    const char* nbytes = (const char*)nmat;          // 256 B per row

    // A fragments: a[s][kc], row = rbase + s*32 + lo, k-bytes = kc*32 + hi*16
    bf16x8 afrag[2][8];
    #pragma unroll
    for (int s = 0; s < 2; s++) {
        const char* rowp = nbytes + (size_t)(rbase + s * 32 + lo) * 256 + hi * 16;
        #pragma unroll
        for (int kc = 0; kc < 8; kc++)
            afrag[s][kc] = *(const bf16x8*)(rowp + kc * 32);
    }

    float sums[2][16];
    #pragma unroll
    for (int s = 0; s < 2; s++)
        #pragma unroll
        for (int r = 0; r < 16; r++) sums[s][r] = 0.f;

    floatx16 zero = {};

    for (int t = 0; t < TILES; t++) {
        const int tc = cbase + t * TILE_COLS;
        __syncthreads();
        {   // stage B tile: thread t -> col c = t>>3, 32 B chunk part = t&7
            int c = tid >> 3, part = tid & 7;
            const char* g = nbytes + (size_t)(tc + c) * 256 + part * 32;
            uint4 g0 = *(const uint4*)g;
            uint4 g1 = *(const uint4*)(g + 16);
            int u0 = part * 2, u1 = u0 + 1;
            *(uint4*)&lds[u0 * 512 + ((c ^ u0) & 31) * 16] = g0;
            *(uint4*)&lds[u1 * 512 + ((c ^ u1) & 31) * 16] = g1;
        }
        __syncthreads();

        floatx16 acc0 = zero, acc1 = zero;
        #pragma unroll
        for (int kc = 0; kc < 8; kc++) {
            int u = kc * 2 + hi;
            bf16x8 bfrag = *(const bf16x8*)&lds[u * 512 + ((lo ^ u) & 31) * 16];
            acc0 = __builtin_amdgcn_mfma_f32_32x32x16_bf16(afrag[0][kc], bfrag, acc0, 0, 0, 0);
            acc1 = __builtin_amdgcn_mfma_f32_32x32x16_bf16(afrag[1][kc], bfrag, acc1, 0, 0, 0);
        }

        // epilogue: e = exp(s_ij), mask diagonal, accumulate per-lane row sums
        #pragma unroll
        for (int s = 0; s < 2; s++) {
            const floatx16& acc = s ? acc1 : acc0;
            bool dtile = (tc == rbase + s * 32);   // 32-aligned, exact overlap test
            #pragma unroll
            for (int r = 0; r < 16; r++) {
                float e = exp2f(acc[r] * SCALE);
                // C/D layout (m74/m101): col=lo, row=(r&3)+8*(r>>2)+4*hi
                if (dtile && lo == ((r & 3) + 8 * (r >> 2) + 4 * hi)) e = 0.f;
                sums[s][r] += e;
            }
        }
    }

    // reduce across the 32 lanes (cols) sharing hi
    #pragma unroll
    for (int s = 0; s < 2; s++)
        #pragma unroll
        for (int r = 0; r < 16; r++) {
            float v = sums[s][r];
            #pragma unroll
            for (int off = 1; off < 32; off <<= 1) v += __shfl_xor(v, off);
            sums[s][r] = v;
        }
    if (lo == 0) {
        #pragma unroll
        for (int s = 0; s < 2; s++)
            #pragma unroll
            for (int r = 0; r < 16; r++) {
                int grow = rbase + s * 32 + (r & 3) + 8 * (r >> 2) + 4 * hi;
                atomicAdd(&sumexp[grow], sums[s][r]);
            }
    }
}

// ---------------- finalize: loss = (sum log(se) - 2*sum spos)/N ----------------
__global__ void final_k(const float* __restrict__ sumexp, const float* __restrict__ spos,
                        float* __restrict__ out) {
    __shared__ float red[8];
    int tid = threadIdx.x;   // 512 threads
    float acc = 0.f;
    for (int i = tid; i < Nrows; i += 512) acc += logf(sumexp[i]);
    for (int i = tid; i < Bsz;   i += 512) acc -= 2.f * spos[i];
    #pragma unroll
    for (int off = 32; off; off >>= 1) acc += __shfl_xor(acc, off);
    if ((tid & 63) == 0) red[tid >> 6] = acc;
    __syncthreads();
    if (tid == 0) {
        float tt = 0.f;
        for (int w = 0; w < 8; w++) tt += red[w];
        out[0] = tt / (float)Nrows;
    }
}

extern "C" void kernel_launch(void* const* d_in, const int* in_sizes, int n_in,
                              void* d_out, int out_size, void* d_ws, size_t ws_size,
                              hipStream_t stream) {
    const float* f = (const float*)d_in[0];
    char* ws = (char*)d_ws;
    __hip_bfloat16* nmat = (__hip_bfloat16*)ws;                       // 2 MB
    float* sumexp = (float*)(ws + (size_t)Nrows * Dd * 2);            // 32 KB
    float* spos   = (float*)(ws + (size_t)Nrows * Dd * 2 + Nrows * 4);// 16 KB

    hipMemsetAsync(sumexp, 0, Nrows * sizeof(float), stream);
    normalize_k<<<Nrows / 4, 256, 0, stream>>>(f, nmat);
    pos_k<<<Bsz / 4, 256, 0, stream>>>(f, spos);
    dim3 grid(CHUNKS, Nrows / 256);
    main_k<<<grid, 256, 0, stream>>>(nmat, sumexp);
    final_k<<<1, 512, 0, stream>>>(sumexp, spos, (float*)d_out);
}

// Round 2
// 87.939 us; speedup vs baseline: 1.1227x; 1.1227x over previous
//
#include <hip/hip_runtime.h>
#include <hip/hip_bf16.h>
#include <math.h>

// SupConLoss, B=4096 V=2 D=128, N=8192.
// loss = (1/N) [ sum_i log(sum_{j!=i} exp(n_i.n_j/T)) - 2*sum_b spos_b ]
// Round 2: 3 launches (prep, main, final); no memset/atomics; A pre-scaled by
// log2(e)/T so epilogue is pure exp2; native v_log_f32 in finalize.

constexpr int   Bsz   = 4096;
constexpr int   Nrows = 8192;
constexpr int   Dd    = 128;
constexpr float TEMPf = 0.07f;
constexpr float EPSN  = 1e-8f;
constexpr float SCALE = 1.4426950408889634f / 0.07f;  // log2(e)/T
constexpr float LN2   = 0.6931471805599453f;

constexpr int CHUNKS     = 16;                     // column chunks (grid.x)
constexpr int CHUNK_COLS = Nrows / CHUNKS;         // 512
constexpr int TILE_COLS  = 32;
constexpr int TILES      = CHUNK_COLS / TILE_COLS; // 16

typedef __attribute__((ext_vector_type(8)))  short bf16x8;   // 8 bf16 = 4 VGPRs
typedef __attribute__((ext_vector_type(16))) float floatx16; // MFMA 32x32 C/D

// ws: [0,2MB) nB bf16[8192][128]; [2MB,4MB) nA (SCALE-scaled) bf16[8192][128];
//     [4MB,+512KB) partial f32[16][8192]; then spos f32[4096]

// ------------- prep: normalize both views of a sample + pair dot ---------------
// One wave per sample b. Rows: view0 -> b, view1 -> Bsz+b (view-major concat).
__global__ void prep_k(const float* __restrict__ f,
                       __hip_bfloat16* __restrict__ nB,
                       __hip_bfloat16* __restrict__ nA,
                       float* __restrict__ spos) {
    int b    = blockIdx.x * 4 + (threadIdx.x >> 6);
    int lane = threadIdx.x & 63;
    const float* s0 = f + (size_t)(b * 2) * Dd;       // features[b, 0, :]
    float2 x = *(const float2*)(s0 + lane * 2);       // view 0
    float2 y = *(const float2*)(s0 + Dd + lane * 2);  // view 1
    float ss0 = x.x * x.x + x.y * x.y;
    float ss1 = y.x * y.x + y.y * y.y;
    float dt  = x.x * y.x + x.y * y.y;
    #pragma unroll
    for (int off = 32; off; off >>= 1) {
        ss0 += __shfl_xor(ss0, off);
        ss1 += __shfl_xor(ss1, off);
        dt  += __shfl_xor(dt,  off);
    }
    float inv0 = 1.0f / fmaxf(sqrtf(ss0), EPSN);
    float inv1 = 1.0f / fmaxf(sqrtf(ss1), EPSN);
    __hip_bfloat162 h;
    h.x = __float2bfloat16(x.x * inv0);
    h.y = __float2bfloat16(x.y * inv0);
    *(__hip_bfloat162*)(nB + (size_t)b * Dd + lane * 2) = h;
    h.x = __float2bfloat16(x.x * inv0 * SCALE);
    h.y = __float2bfloat16(x.y * inv0 * SCALE);
    *(__hip_bfloat162*)(nA + (size_t)b * Dd + lane * 2) = h;
    h.x = __float2bfloat16(y.x * inv1);
    h.y = __float2bfloat16(y.y * inv1);
    *(__hip_bfloat162*)(nB + (size_t)(Bsz + b) * Dd + lane * 2) = h;
    h.x = __float2bfloat16(y.x * inv1 * SCALE);
    h.y = __float2bfloat16(y.y * inv1 * SCALE);
    *(__hip_bfloat162*)(nA + (size_t)(Bsz + b) * Dd + lane * 2) = h;
    if (lane == 0) spos[b] = dt * inv0 * inv1 / TEMPf;
}

// ------------- main: fused nA·nB^T -> exp2 -> per-chunk row sums ---------------
// Block: 256 thr (4 waves). Wave tile: 64 rows x 32 cols, K=128.
// A (64 rows x 128, pre-scaled) in registers; B tile staged in 8 KB LDS,
// [k-unit u][col] with XOR swizzle (conflict-free b128 reads).
__global__ __launch_bounds__(256, 2)
void main_k(const __hip_bfloat16* __restrict__ nA, const __hip_bfloat16* __restrict__ nB,
            float* __restrict__ partial) {
    __shared__ char lds[TILE_COLS * 256];   // 8 KB: 16 units x 32 cols x 16 B
    const int tid  = threadIdx.x;
    const int wid  = tid >> 6;
    const int lane = tid & 63;
    const int lo   = lane & 31;
    const int hi   = lane >> 5;
    const int rbase = blockIdx.y * 256 + wid * 64;   // wave's 64 rows
    const int cbase = blockIdx.x * CHUNK_COLS;
    const char* abytes = (const char*)nA;            // 256 B per row
    const char* bbytes = (const char*)nB;

    // A fragments: row = rbase + s*32 + lo, k-bytes = kc*32 + hi*16
    bf16x8 afrag[2][8];
    #pragma unroll
    for (int s = 0; s < 2; s++) {
        const char* rowp = abytes + (size_t)(rbase + s * 32 + lo) * 256 + hi * 16;
        #pragma unroll
        for (int kc = 0; kc < 8; kc++)
            afrag[s][kc] = *(const bf16x8*)(rowp + kc * 32);
    }

    float sums[2][16];
    #pragma unroll
    for (int s = 0; s < 2; s++)
        #pragma unroll
        for (int r = 0; r < 16; r++) sums[s][r] = 0.f;

    floatx16 zero = {};

    for (int t = 0; t < TILES; t++) {
        const int tc = cbase + t * TILE_COLS;
        __syncthreads();
        {   // stage B tile: thread t -> col c = t>>3, 32 B part = t&7 (coalesced)
            int c = tid >> 3, part = tid & 7;
            const char* g = bbytes + (size_t)(tc + c) * 256 + part * 32;
            uint4 g0 = *(const uint4*)g;
            uint4 g1 = *(const uint4*)(g + 16);
            int u0 = part * 2, u1 = u0 + 1;
            *(uint4*)&lds[u0 * 512 + ((c ^ u0) & 31) * 16] = g0;
            *(uint4*)&lds[u1 * 512 + ((c ^ u1) & 31) * 16] = g1;
        }
        __syncthreads();

        floatx16 acc0 = zero, acc1 = zero;
        #pragma unroll
        for (int kc = 0; kc < 8; kc++) {
            int u = kc * 2 + hi;
            bf16x8 bfrag = *(const bf16x8*)&lds[u * 512 + ((lo ^ u) & 31) * 16];
            acc0 = __builtin_amdgcn_mfma_f32_32x32x16_bf16(afrag[0][kc], bfrag, acc0, 0, 0, 0);
            acc1 = __builtin_amdgcn_mfma_f32_32x32x16_bf16(afrag[1][kc], bfrag, acc1, 0, 0, 0);
        }

        // epilogue: e = exp2(acc) (scale pre-folded), mask diagonal, accumulate
        #pragma unroll
        for (int s = 0; s < 2; s++) {
            const floatx16& acc = s ? acc1 : acc0;
            bool dtile = (tc == rbase + s * 32);   // 32-aligned exact overlap test
            #pragma unroll
            for (int r = 0; r < 16; r++) {
                float e = __builtin_amdgcn_exp2f(acc[r]);
                // C/D layout (m74/m101): col=lo, row=(r&3)+8*(r>>2)+4*hi
                if (dtile && lo == ((r & 3) + 8 * (r >> 2) + 4 * hi)) e = 0.f;
                sums[s][r] += e;
            }
        }
    }

    // reduce across the 32 lanes (cols) sharing hi; store per-chunk partials
    #pragma unroll
    for (int s = 0; s < 2; s++)
        #pragma unroll
        for (int r = 0; r < 16; r++) {
            float v = sums[s][r];
            #pragma unroll
            for (int off = 1; off < 32; off <<= 1) v += __shfl_xor(v, off);
            sums[s][r] = v;
        }
    if (lo == 0) {
        float* prow = partial + (size_t)blockIdx.x * Nrows;
        #pragma unroll
        for (int s = 0; s < 2; s++)
            #pragma unroll
            for (int r = 0; r < 16; r++) {
                int grow = rbase + s * 32 + (r & 3) + 8 * (r >> 2) + 4 * hi;
                prow[grow] = sums[s][r];
            }
    }
}

// ------------- finalize: loss = (sum log(se) - 2*sum spos)/N -------------------
__global__ __launch_bounds__(1024)
void final_k(const float* __restrict__ partial, const float* __restrict__ spos,
             float* __restrict__ out) {
    __shared__ float red[16];
    int tid = threadIdx.x;   // 1024 threads
    float acc = 0.f;
    for (int r = tid; r < Nrows; r += 1024) {
        float se = 0.f;
        #pragma unroll
        for (int c = 0; c < CHUNKS; c++) se += partial[(size_t)c * Nrows + r];
        acc += __builtin_amdgcn_logf(se) * LN2;   // v_log_f32 is log2
    }
    for (int b = tid; b < Bsz; b += 1024) acc -= 2.f * spos[b];
    #pragma unroll
    for (int off = 32; off; off >>= 1) acc += __shfl_xor(acc, off);
    if ((tid & 63) == 0) red[tid >> 6] = acc;
    __syncthreads();
    if (tid == 0) {
        float tt = 0.f;
        for (int w = 0; w < 16; w++) tt += red[w];
        out[0] = tt / (float)Nrows;
    }
}

extern "C" void kernel_launch(void* const* d_in, const int* in_sizes, int n_in,
                              void* d_out, int out_size, void* d_ws, size_t ws_size,
                              hipStream_t stream) {
    const float* f = (const float*)d_in[0];
    char* ws = (char*)d_ws;
    __hip_bfloat16* nB = (__hip_bfloat16*)ws;                              // 2 MB
    __hip_bfloat16* nA = (__hip_bfloat16*)(ws + (size_t)Nrows * Dd * 2);   // 2 MB
    float* partial = (float*)(ws + (size_t)2 * Nrows * Dd * 2);            // 512 KB
    float* spos    = (float*)(ws + (size_t)2 * Nrows * Dd * 2
                                 + (size_t)CHUNKS * Nrows * 4);            // 16 KB

    prep_k<<<Bsz / 4, 256, 0, stream>>>(f, nB, nA, spos);
    dim3 grid(CHUNKS, Nrows / 256);
    main_k<<<grid, 256, 0, stream>>>(nA, nB, partial);
    final_k<<<1, 1024, 0, stream>>>(partial, spos, (float*)d_out);
}